// Round 3
// baseline (2830.966 us; speedup 1.0000x reference)
//
#include <hip/hip_runtime.h>

#define NN 50000
#define NE 400000
#define HID 768
#define NL 4

typedef short bf16x8_t __attribute__((ext_vector_type(8)));
typedef float f32x4_t __attribute__((ext_vector_type(4)));

__device__ __forceinline__ unsigned short f2bf(float f) {
  union { float f; unsigned int u; } c; c.f = f;
  unsigned int u = c.u;
  u += 0x7FFF + ((u >> 16) & 1);   // round-to-nearest-even
  return (unsigned short)(u >> 16);
}
__device__ __forceinline__ float bf2f(unsigned short s) {
  union { unsigned int u; float f; } c; c.u = ((unsigned int)s) << 16;
  return c.f;
}

// async global->LDS, 16B per lane; LDS dest = base + lane*16 (wave-uniform base)
__device__ __forceinline__ void async16(const void* g, void* l) {
  __builtin_amdgcn_global_load_lds((const __attribute__((address_space(1))) void*)g,
                                   (__attribute__((address_space(3))) void*)l,
                                   16, 0, 0);
}

// ---- zero deg + cursor ----
__global__ void k_zero2(int* __restrict__ a, int* __restrict__ b, int n) {
  int i = blockIdx.x * blockDim.x + threadIdx.x;
  if (i < n) { a[i] = 0; b[i] = 0; }
}

// ---- fp32 -> bf16 weight conversion ----
__global__ void k_cvt(const float* __restrict__ a, unsigned short* __restrict__ o, int n) {
  int i = blockIdx.x * blockDim.x + threadIdx.x;
  if (i < n) o[i] = f2bf(a[i]);
}

// ---- input projection: h = x @ Wp.T + bp  (x: [NN,8], Wp: [HID,8]) ----
__global__ __launch_bounds__(256) void k_inproj(const float* __restrict__ x,
                                                const float* __restrict__ Wp,
                                                const float* __restrict__ bp,
                                                unsigned short* __restrict__ h) {
  int n = blockIdx.x;
  __shared__ float xs[8];
  if (threadIdx.x < 8) xs[threadIdx.x] = x[n * 8 + threadIdx.x];
  __syncthreads();
  for (int j = threadIdx.x; j < HID; j += 256) {
    const float* w = Wp + j * 8;
    float s = bp[j];
#pragma unroll
    for (int k = 0; k < 8; ++k) s += xs[k] * w[k];
    h[(size_t)n * HID + j] = f2bf(s);
  }
}

// ---- degree count ----
__global__ void k_deg(const int* __restrict__ dst, int* __restrict__ deg) {
  int i = blockIdx.x * blockDim.x + threadIdx.x;
  if (i < NE) atomicAdd(&deg[dst[i]], 1);
}

// ---- exclusive scan over deg -> rowptr (single block) ----
__global__ __launch_bounds__(1024) void k_scan(const int* __restrict__ deg, int* __restrict__ rowptr) {
  __shared__ int sm[1024];
  const int chunk = 49;  // ceil(50000/1024)
  int t = threadIdx.x;
  int start = t * chunk;
  int end = min(start + chunk, NN);
  int local = 0;
  for (int i = start; i < end; ++i) local += deg[i];
  sm[t] = local;
  __syncthreads();
  for (int off = 1; off < 1024; off <<= 1) {
    int v = (t >= off) ? sm[t - off] : 0;
    __syncthreads();
    sm[t] += v;
    __syncthreads();
  }
  int run = sm[t] - local;  // exclusive prefix
  for (int i = start; i < end; ++i) { rowptr[i] = run; run += deg[i]; }
  if (start < NN && end == NN) rowptr[NN] = run;
}

// ---- CSR fill ----
__global__ void k_fill(const int* __restrict__ src, const int* __restrict__ dst,
                       const int* __restrict__ rowptr, int* __restrict__ cursor,
                       int* __restrict__ csr) {
  int i = blockIdx.x * blockDim.x + threadIdx.x;
  if (i < NE) {
    int d = dst[i];
    int pos = atomicAdd(&cursor[d], 1);
    csr[rowptr[d] + pos] = src[i];
  }
}

// ---- mean aggregation: agg[n] = mean over neighbors of h[src] ----
__global__ __launch_bounds__(192) void k_agg(const unsigned short* __restrict__ h,
                                             const int* __restrict__ csr,
                                             const int* __restrict__ rowptr,
                                             unsigned short* __restrict__ agg) {
  int n = blockIdx.x;
  int t = threadIdx.x;
  int beg = rowptr[n], end = rowptr[n + 1];
  float a0 = 0.f, a1 = 0.f, a2 = 0.f, a3 = 0.f;
  for (int i = beg; i < end; ++i) {
    int s = csr[i];
    ushort4 v = *(const ushort4*)(h + (size_t)s * HID + t * 4);
    a0 += bf2f(v.x); a1 += bf2f(v.y); a2 += bf2f(v.z); a3 += bf2f(v.w);
  }
  float inv = 1.0f / (float)max(end - beg, 1);
  ushort4 o;
  o.x = f2bf(a0 * inv); o.y = f2bf(a1 * inv); o.z = f2bf(a2 * inv); o.w = f2bf(a3 * inv);
  *(ushort4*)(agg + (size_t)n * HID + t * 4) = o;
}

// ---- fused GEMM: sact = silu(agg@Wl.T + h@Wr.T + bl)  (bf16 MFMA, bf16 out)
//
// R3: decouple the A path from workgroup sync. Diagnosis: R0/R1/R2 all ~220us
// @22% MfmaUtil because all waves move in lockstep (barrier+drain per step)
// and the A operand is COLD (single-use, written by previous kernel) -> every
// A staging wait exposes L3 latency to the whole workgroup.
// Design: tile 256x128, 8 waves (wave=128x32, acc 8x2 f32x4 = 64 regs).
//  * A: NO LDS. Per-wave register pipeline, depth 3, NAMED sets aS0/1/2
//    (static indexing, rule #20). Loads are global_load_dwordx4 with uniform
//    SGPR base (per-tile koff) + fixed per-lane voffset -> ~0 VALU per tile.
//    HW scoreboard + compiler's exact counted waitcnt hide A latency PER-WAVE.
//  * B (weights, L2-hot): 4-slot LDS ring (4 x 8KB), one async16/thread/tile,
//    pre-swizzled source kg^=(rl>>1)&3, same XOR on ds_read (0 conflicts).
//  * Per K-tile: one counted vmcnt(18) (B-publish; slack ~2.7 bodies), two raw
//    s_barriers, 2 ds_read_b128/wave, 16 MFMA/wave, setprio around MFMA.
//    Prefetch clump (8 A-loads + 1 B-DMA = 9 vmcnt units/body) pinned with
//    sched_barrier(0) so the ledger stays exact. Tail: W=18,18,9,0.
//  * Grid 196 bands x 6 N-tiles = 1176 = 8*147 (bijective XCD map); the 6
//    blocks of a band share the A panel (768KB, fits 4MB XCD L2) -> cold A
//    read from L3 once, then L2-hit. Within a block, 4 waves share A rows
//    (16KB/tile, fits L1).
#define BM 256
#define BN 128
#define NKT 48       // 2 gemm phases x (768/32); pointer switch at tile 24
#define GGRID 1176

__global__ __launch_bounds__(512, 2) void k_gemm(const unsigned short* __restrict__ A0,  // agg
                                                 const unsigned short* __restrict__ A1,  // h
                                                 const unsigned short* __restrict__ B0,  // Wl (bf16, [j,k])
                                                 const unsigned short* __restrict__ B1,  // Wr
                                                 const float* __restrict__ bias,
                                                 unsigned short* __restrict__ sact, int M) {
  __shared__ __align__(16) unsigned short Bs[4][BN * 32];  // 32 KiB total

  int b = blockIdx.x;
  int xcd = b & 7, jj = b >> 3;
  int o = xcd * 147 + jj;          // 1176 = 8*147 exact, bijective
  int band = o / 6, nt6 = o % 6;   // 6 N-tiles of a band stay on one XCD
  int m0 = band * BM, n0 = nt6 * BN;

  int tid = threadIdx.x, lane = tid & 63, w = tid >> 6;
  int wm = w >> 2, wn = w & 3;     // wave tile: rows wm*128..+128, cols wn*32..+32

  // ---- B staging: one async16/thread; linear LDS dest, pre-swizzled source ----
  int rl = tid >> 2;                               // 0..127 (row in B tile)
  int kgs = (tid & 3) ^ ((rl >> 1) & 3);           // swizzled col-group
  size_t bsrc = (size_t)(n0 + rl) * (HID * 2) + kgs * 16;  // byte offset in weight buf

  // ---- A-frag per-lane byte voffsets (constant; SGPR base carries m0+koff) ----
  int mr = lane & 15, kq = lane >> 4;
  unsigned voffA[8];
#pragma unroll
  for (int i = 0; i < 8; ++i)
    voffA[i] = (unsigned)(((wm * 128 + i * 16 + mr) * HID + kq * 8) * 2);

  // ---- B ds_read element offsets (swizzle depends only on mr) ----
  int sq = (kq ^ ((mr >> 1) & 3)) * 8;
  int boffe[2];
#pragma unroll
  for (int nt = 0; nt < 2; ++nt)
    boffe[nt] = (wn * 32 + nt * 16 + mr) * 32 + sq;

  const char* Abase0 = (const char*)A0 + (size_t)m0 * (HID * 2);
  const char* Abase1 = (const char*)A1 + (size_t)m0 * (HID * 2);

  f32x4_t acc[8][2] = {};
  bf16x8_t aS0[8], aS1[8], aS2[8];   // A(t) lives in set t%3

  auto loadA = [&](int tt, bf16x8_t (&af)[8]) {
    const char* Ab = (tt < 24 ? Abase0 : Abase1) + (size_t)(tt < 24 ? tt : tt - 24) * 64;
#pragma unroll
    for (int i = 0; i < 8; ++i) af[i] = *(const bf16x8_t*)(Ab + voffA[i]);
  };
  auto stageB = [&](int tt) {
    const char* Bb = (const char*)(tt < 24 ? B0 : B1) + (size_t)(tt < 24 ? tt : tt - 24) * 64;
    async16(Bb + bsrc, &Bs[tt & 3][w * 512]);
  };

  // body(t): wait W -> publish barrier -> ds_read B(t) -> MFMA(A set, B) ->
  //          prefetch group t+3 (9 vmcnt units, pinned) -> end barrier.
  auto body = [&](int t, bf16x8_t (&af)[8], int W) {
    if (W == 18)      asm volatile("s_waitcnt vmcnt(18)" ::: "memory");
    else if (W == 9)  asm volatile("s_waitcnt vmcnt(9)" ::: "memory");
    else              asm volatile("s_waitcnt vmcnt(0)" ::: "memory");
    __builtin_amdgcn_s_barrier();                  // B(t) published
    int s = t & 3;
    bf16x8_t bf0 = *(const bf16x8_t*)&Bs[s][boffe[0]];
    bf16x8_t bf1 = *(const bf16x8_t*)&Bs[s][boffe[1]];
    asm volatile("s_waitcnt lgkmcnt(0)" ::: "memory");
    __builtin_amdgcn_sched_barrier(0);             // rule #18
    __builtin_amdgcn_s_setprio(1);
#pragma unroll
    for (int mt = 0; mt < 8; ++mt) {
      acc[mt][0] = __builtin_amdgcn_mfma_f32_16x16x32_bf16(af[mt], bf0, acc[mt][0], 0, 0, 0);
      acc[mt][1] = __builtin_amdgcn_mfma_f32_16x16x32_bf16(af[mt], bf1, acc[mt][1], 0, 0, 0);
    }
    __builtin_amdgcn_s_setprio(0);
    __builtin_amdgcn_sched_barrier(0);             // pin prefetch clump start
    int tt = t + 3;
    if (tt < NKT) { loadA(tt, af); stageB(tt); }   // refills set t%3 (WAR-safe: after use)
    __builtin_amdgcn_sched_barrier(0);             // pin prefetch clump end
    __builtin_amdgcn_s_barrier();                  // slot/set reuse fence
  };

  // prologue: groups 0,1,2 (9 units each, order pinned)
  loadA(0, aS0); stageB(0); __builtin_amdgcn_sched_barrier(0);
  loadA(1, aS1); stageB(1); __builtin_amdgcn_sched_barrier(0);
  loadA(2, aS2); stageB(2); __builtin_amdgcn_sched_barrier(0);

  for (int t = 0; t < 45; t += 3) {   // bodies 0..44
    body(t,     aS0, 18);
    body(t + 1, aS1, 18);
    body(t + 2, aS2, 18);
  }
  body(45, aS0, 18);
  body(46, aS1, 9);
  body(47, aS2, 0);

  // epilogue: C(row=(lane>>4)*4+r, col=lane&15); fuse bias + silu, store bf16
  int col = lane & 15;
  int rq = (lane >> 4) * 4;
#pragma unroll
  for (int mt = 0; mt < 8; ++mt) {
#pragma unroll
    for (int nt = 0; nt < 2; ++nt) {
      int jc = n0 + wn * 32 + nt * 16 + col;
      float bv = bias[jc];
#pragma unroll
      for (int r = 0; r < 4; ++r) {
        int gm = m0 + wm * 128 + mt * 16 + rq + r;
        if (gm < M) {
          float v = acc[mt][nt][r] + bv;
          float sv = v / (1.f + __expf(-v));
          sact[(size_t)gm * HID + jc] = f2bf(sv);
        }
      }
    }
  }
}

// ---- LayerNorm over bf16 silu activations; write bf16 h or fp32 final out ----
__global__ __launch_bounds__(256) void k_ln(const unsigned short* __restrict__ sact,
                                            const float* __restrict__ gamma,
                                            const float* __restrict__ beta,
                                            unsigned short* __restrict__ hout,
                                            float* __restrict__ fout) {
  int n = blockIdx.x;
  const unsigned short* p = sact + (size_t)n * HID;
  float v[3];
  float sum = 0.f, sq = 0.f;
#pragma unroll
  for (int i = 0; i < 3; ++i) {
    float s = bf2f(p[threadIdx.x + i * 256]);
    v[i] = s; sum += s; sq += s * s;
  }
#pragma unroll
  for (int off = 32; off >= 1; off >>= 1) {
    sum += __shfl_down(sum, off);
    sq  += __shfl_down(sq, off);
  }
  __shared__ float rs[4], rq2[4];
  int wv = threadIdx.x >> 6;
  if ((threadIdx.x & 63) == 0) { rs[wv] = sum; rq2[wv] = sq; }
  __syncthreads();
  if (threadIdx.x == 0) {
    float s = rs[0] + rs[1] + rs[2] + rs[3];
    float q = rq2[0] + rq2[1] + rq2[2] + rq2[3];
    rs[0] = s / (float)HID;
    rq2[0] = q / (float)HID;
  }
  __syncthreads();
  float mu = rs[0];
  float var = rq2[0] - mu * mu;
  float inv = rsqrtf(var + 1e-5f);
#pragma unroll
  for (int i = 0; i < 3; ++i) {
    int j = threadIdx.x + i * 256;
    float y = (v[i] - mu) * inv * gamma[j] + beta[j];
    if (fout) fout[(size_t)n * HID + j] = y;
    else      hout[(size_t)n * HID + j] = f2bf(y);
  }
}

extern "C" void kernel_launch(void* const* d_in, const int* in_sizes, int n_in,
                              void* d_out, int out_size, void* d_ws, size_t ws_size,
                              hipStream_t stream) {
  const float* x     = (const float*)d_in[0];
  const float* Wp    = (const float*)d_in[1];
  const float* bp    = (const float*)d_in[2];
  const float* Wl    = (const float*)d_in[3];
  const float* bl    = (const float*)d_in[4];
  const float* Wr    = (const float*)d_in[5];
  const float* gamma = (const float*)d_in[6];
  const float* beta  = (const float*)d_in[7];
  const int*   ei    = (const int*)d_in[8];
  float* out = (float*)d_out;

  const int* src = ei;
  const int* dst = ei + NE;

  // workspace carve (all offsets 16B-aligned).
  // NOTE: k_gemm reads A rows up to m0+255 (<= 50175) unconditionally; rows
  // >= NN read into the NEXT buffer in this carve — allocated, harmless
  // (results masked on store). Keep h, agg, sact adjacent and in this order.
  char* p = (char*)d_ws;
  unsigned short* h    = (unsigned short*)p;              p += (size_t)NN * HID * 2;  // 76.8 MB
  unsigned short* agg  = (unsigned short*)p;              p += (size_t)NN * HID * 2;  // 76.8 MB
  unsigned short* sact = (unsigned short*)p;              p += (size_t)NN * HID * 2;  // 76.8 MB
  unsigned short* Wlb  = (unsigned short*)p;              p += (size_t)NL * HID * HID * 2;
  unsigned short* Wrb  = (unsigned short*)p;              p += (size_t)NL * HID * HID * 2;
  int* deg             = (int*)p;                         p += (size_t)NN * 4;
  int* rowptr          = (int*)p;                         p += (size_t)(NN + 1) * 4 + 12;
  int* cursor          = (int*)p;                         p += (size_t)NN * 4;
  int* csr             = (int*)p;                         p += (size_t)NE * 4;

  // graph build + weight prep
  k_zero2<<<(NN + 255) / 256, 256, 0, stream>>>(deg, cursor, NN);
  int wn = NL * HID * HID;
  k_cvt<<<(wn + 255) / 256, 256, 0, stream>>>(Wl, Wlb, wn);
  k_cvt<<<(wn + 255) / 256, 256, 0, stream>>>(Wr, Wrb, wn);
  k_inproj<<<NN, 256, 0, stream>>>(x, Wp, bp, h);
  k_deg<<<(NE + 255) / 256, 256, 0, stream>>>(dst, deg);
  k_scan<<<1, 1024, 0, stream>>>(deg, rowptr);
  k_fill<<<(NE + 255) / 256, 256, 0, stream>>>(src, dst, rowptr, cursor, csr);

  for (int l = 0; l < NL; ++l) {
    k_agg<<<NN, 192, 0, stream>>>(h, csr, rowptr, agg);
    k_gemm<<<GGRID, 512, 0, stream>>>(agg, h,
                                      Wlb + (size_t)l * HID * HID,
                                      Wrb + (size_t)l * HID * HID,
                                      bl + (size_t)l * HID, sact, NN);
    k_ln<<<NN, 256, 0, stream>>>(sact, gamma + (size_t)l * HID, beta + (size_t)l * HID,
                                 h, (l == NL - 1) ? out : nullptr);
  }
}

// Round 4
// 1594.427 us; speedup vs baseline: 1.7755x; 1.7755x over previous
//
#include <hip/hip_runtime.h>

#define NN 50000
#define NE 400000
#define HID 768
#define NL 4

typedef short bf16x8_t __attribute__((ext_vector_type(8)));
typedef float f32x4_t __attribute__((ext_vector_type(4)));

__device__ __forceinline__ unsigned short f2bf(float f) {
  union { float f; unsigned int u; } c; c.f = f;
  unsigned int u = c.u;
  u += 0x7FFF + ((u >> 16) & 1);   // round-to-nearest-even
  return (unsigned short)(u >> 16);
}
__device__ __forceinline__ float bf2f(unsigned short s) {
  union { unsigned int u; float f; } c; c.u = ((unsigned int)s) << 16;
  return c.f;
}

// async global->LDS, 16B per lane; LDS dest = base + lane*16 (wave-uniform base)
__device__ __forceinline__ void async16(const void* g, void* l) {
  __builtin_amdgcn_global_load_lds((const __attribute__((address_space(1))) void*)g,
                                   (__attribute__((address_space(3))) void*)l,
                                   16, 0, 0);
}

// ---- zero deg + cursor ----
__global__ void k_zero2(int* __restrict__ a, int* __restrict__ b, int n) {
  int i = blockIdx.x * blockDim.x + threadIdx.x;
  if (i < n) { a[i] = 0; b[i] = 0; }
}

// ---- fp32 -> bf16 weight conversion (vectorized x4) ----
__global__ void k_cvt(const float* __restrict__ a, unsigned short* __restrict__ o, int n4) {
  int i = blockIdx.x * blockDim.x + threadIdx.x;
  if (i < n4) {
    float4 f = *(const float4*)(a + (size_t)i * 4);
    ushort4 u;
    u.x = f2bf(f.x); u.y = f2bf(f.y); u.z = f2bf(f.z); u.w = f2bf(f.w);
    *(ushort4*)(o + (size_t)i * 4) = u;
  }
}

// ---- input projection: h = x @ Wp.T + bp  (x: [NN,8], Wp: [HID,8]) ----
__global__ __launch_bounds__(256) void k_inproj(const float* __restrict__ x,
                                                const float* __restrict__ Wp,
                                                const float* __restrict__ bp,
                                                unsigned short* __restrict__ h) {
  int n = blockIdx.x;
  __shared__ float xs[8];
  if (threadIdx.x < 8) xs[threadIdx.x] = x[n * 8 + threadIdx.x];
  __syncthreads();
  for (int j = threadIdx.x; j < HID; j += 256) {
    const float* w = Wp + j * 8;
    float s = bp[j];
#pragma unroll
    for (int k = 0; k < 8; ++k) s += xs[k] * w[k];
    h[(size_t)n * HID + j] = f2bf(s);
  }
}

// ---- degree count ----
__global__ void k_deg(const int* __restrict__ dst, int* __restrict__ deg) {
  int i = blockIdx.x * blockDim.x + threadIdx.x;
  if (i < NE) atomicAdd(&deg[dst[i]], 1);
}

// ---- exclusive scan over deg -> rowptr (single block) ----
__global__ __launch_bounds__(1024) void k_scan(const int* __restrict__ deg, int* __restrict__ rowptr) {
  __shared__ int sm[1024];
  const int chunk = 49;  // ceil(50000/1024)
  int t = threadIdx.x;
  int start = t * chunk;
  int end = min(start + chunk, NN);
  int local = 0;
  for (int i = start; i < end; ++i) local += deg[i];
  sm[t] = local;
  __syncthreads();
  for (int off = 1; off < 1024; off <<= 1) {
    int v = (t >= off) ? sm[t - off] : 0;
    __syncthreads();
    sm[t] += v;
    __syncthreads();
  }
  int run = sm[t] - local;  // exclusive prefix
  for (int i = start; i < end; ++i) { rowptr[i] = run; run += deg[i]; }
  if (start < NN && end == NN) rowptr[NN] = run;
}

// ---- CSR fill ----
__global__ void k_fill(const int* __restrict__ src, const int* __restrict__ dst,
                       const int* __restrict__ rowptr, int* __restrict__ cursor,
                       int* __restrict__ csr) {
  int i = blockIdx.x * blockDim.x + threadIdx.x;
  if (i < NE) {
    int d = dst[i];
    int pos = atomicAdd(&cursor[d], 1);
    csr[rowptr[d] + pos] = src[i];
  }
}

// ---- mean aggregation: agg[n] = mean over neighbors of h[src] ----
// R4: batch 4 neighbor indices per iteration to break the csr->h dependent
// chain (4 independent row loads in flight instead of 1). Loads stay
// ushort4 (8B/lane, 192 lanes cover the 1536B row exactly).
__global__ __launch_bounds__(192) void k_agg(const unsigned short* __restrict__ h,
                                             const int* __restrict__ csr,
                                             const int* __restrict__ rowptr,
                                             unsigned short* __restrict__ agg) {
  int n = blockIdx.x;
  int t = threadIdx.x;
  int beg = rowptr[n], end = rowptr[n + 1];
  float a0 = 0.f, a1 = 0.f, a2 = 0.f, a3 = 0.f;
  int i = beg;
  for (; i + 4 <= end; i += 4) {
    int s0 = csr[i], s1 = csr[i + 1], s2 = csr[i + 2], s3 = csr[i + 3];
    ushort4 v0 = *(const ushort4*)(h + (size_t)s0 * HID + t * 4);
    ushort4 v1 = *(const ushort4*)(h + (size_t)s1 * HID + t * 4);
    ushort4 v2 = *(const ushort4*)(h + (size_t)s2 * HID + t * 4);
    ushort4 v3 = *(const ushort4*)(h + (size_t)s3 * HID + t * 4);
    a0 += bf2f(v0.x) + bf2f(v1.x) + bf2f(v2.x) + bf2f(v3.x);
    a1 += bf2f(v0.y) + bf2f(v1.y) + bf2f(v2.y) + bf2f(v3.y);
    a2 += bf2f(v0.z) + bf2f(v1.z) + bf2f(v2.z) + bf2f(v3.z);
    a3 += bf2f(v0.w) + bf2f(v1.w) + bf2f(v2.w) + bf2f(v3.w);
  }
  for (; i < end; ++i) {
    int s = csr[i];
    ushort4 v = *(const ushort4*)(h + (size_t)s * HID + t * 4);
    a0 += bf2f(v.x); a1 += bf2f(v.y); a2 += bf2f(v.z); a3 += bf2f(v.w);
  }
  float inv = 1.0f / (float)max(end - beg, 1);
  ushort4 o;
  o.x = f2bf(a0 * inv); o.y = f2bf(a1 * inv); o.z = f2bf(a2 * inv); o.w = f2bf(a3 * inv);
  *(ushort4*)(agg + (size_t)n * HID + t * 4) = o;
}

// ---- fused GEMM: sact = silu(agg@Wl.T + h@Wr.T + bl)  (bf16 MFMA, bf16 out)
// R1 variant, best measured (211.6us): 224x256 tile, BK=32, 8 waves, 2-slot
// LDS double buffer, 3-tile prefetch, counted vmcnt, raw s_barrier, setprio.
#define BM 224
#define BN 256
#define BKT 32
#define NKT 48       // 2 gemm phases x (768/32)
#define NBANDS 224   // ceil(50000/224); 224*224 = 50176 >= 50000

__global__ __launch_bounds__(512, 2) void k_gemm(const unsigned short* __restrict__ A0,  // agg
                                                 const unsigned short* __restrict__ A1,  // h
                                                 const unsigned short* __restrict__ B0,  // Wl (bf16, [j,k])
                                                 const unsigned short* __restrict__ B1,  // Wr
                                                 const float* __restrict__ bias,
                                                 unsigned short* __restrict__ sact, int M) {
  __shared__ __align__(16) unsigned short As[2][256 * BKT];
  __shared__ __align__(16) unsigned short Bs[2][256 * BKT];

  int b = blockIdx.x;
  int xcd = b & 7;
  int rest = b >> 3;
  int nt3 = rest % 3;          // N-tile: all 3 of a band land on one XCD
  int g = rest / 3;            // 0..27
  int mband = g * 8 + xcd;     // 0..223, exact
  int m0 = mband * BM;
  int n0 = nt3 * BN;

  int tid = threadIdx.x;
  int lane = tid & 63;
  int w = tid >> 6;            // 0..7
  int wm = w >> 2, wn = w & 3; // wave tile: rows wm*112..+112, cols wn*64..+64

  int srow = w * 16 + (lane >> 2);
  int kgg = (lane & 3) ^ ((srow >> 1) & 3);
  size_t aoffg = (size_t)(m0 + srow) * HID + kgg * 8;
  size_t boffg = (size_t)(n0 + srow) * HID + kgg * 8;
  const size_t rstep = (size_t)128 * HID;

  auto stage = [&](int kt, int slot) {
    const unsigned short* A = (kt < 24) ? A0 : A1;
    const unsigned short* B = (kt < 24) ? B0 : B1;
    size_t kk = (size_t)((kt < 24) ? kt : kt - 24) * BKT;
    async16(A + aoffg + kk,         &As[slot][(w * 16) * BKT]);
    async16(B + boffg + kk,         &Bs[slot][(w * 16) * BKT]);
    async16(A + aoffg + rstep + kk, &As[slot][(128 + w * 16) * BKT]);
    async16(B + boffg + rstep + kk, &Bs[slot][(128 + w * 16) * BKT]);
  };

  int mr = lane & 15, kq = lane >> 4;
  int aoff[7], boff[4];
#pragma unroll
  for (int t = 0; t < 7; ++t) {
    int row = wm * 112 + t * 16 + mr;
    aoff[t] = row * BKT + ((kq ^ ((row >> 1) & 3)) * 8);
  }
#pragma unroll
  for (int t = 0; t < 4; ++t) {
    int row = wn * 64 + t * 16 + mr;
    boff[t] = row * BKT + ((kq ^ ((row >> 1) & 3)) * 8);
  }

  f32x4_t acc[7][4] = {};

  stage(0, 0);
  stage(1, 1);

#pragma unroll 2
  for (int T = 0; T < NKT; ++T) {
    int slot = T & 1;
    if (T < NKT - 1) asm volatile("s_waitcnt vmcnt(4)" ::: "memory");
    else             asm volatile("s_waitcnt vmcnt(0)" ::: "memory");
    __builtin_amdgcn_s_barrier();
    asm volatile("" ::: "memory");

    bf16x8_t af[7], bfr[4];
#pragma unroll
    for (int t = 0; t < 7; ++t) af[t] = *(const bf16x8_t*)&As[slot][aoff[t]];
#pragma unroll
    for (int t = 0; t < 4; ++t) bfr[t] = *(const bf16x8_t*)&Bs[slot][boff[t]];

    __builtin_amdgcn_s_setprio(1);
#pragma unroll
    for (int mt = 0; mt < 7; ++mt)
#pragma unroll
      for (int nt = 0; nt < 4; ++nt)
        acc[mt][nt] = __builtin_amdgcn_mfma_f32_16x16x32_bf16(af[mt], bfr[nt], acc[mt][nt], 0, 0, 0);
    __builtin_amdgcn_s_setprio(0);

    asm volatile("s_waitcnt lgkmcnt(0)" ::: "memory");
    __builtin_amdgcn_s_barrier();
    if (T + 2 < NKT) stage(T + 2, slot);
  }

  int col = lane & 15;
  int rq = (lane >> 4) * 4;
#pragma unroll
  for (int mt = 0; mt < 7; ++mt) {
#pragma unroll
    for (int nt = 0; nt < 4; ++nt) {
      int j = n0 + wn * 64 + nt * 16 + col;
      float bv = bias[j];
#pragma unroll
      for (int r = 0; r < 4; ++r) {
        int gm = m0 + wm * 112 + mt * 16 + rq + r;
        if (gm < M) {
          float v = acc[mt][nt][r] + bv;
          float s = v / (1.f + __expf(-v));
          sact[(size_t)gm * HID + j] = f2bf(s);
        }
      }
    }
  }
}

// ---- LayerNorm over bf16 silu activations (vectorized: ushort4/float4) ----
__global__ __launch_bounds__(192) void k_ln(const unsigned short* __restrict__ sact,
                                            const float* __restrict__ gamma,
                                            const float* __restrict__ beta,
                                            unsigned short* __restrict__ hout,
                                            float* __restrict__ fout) {
  int n = blockIdx.x;
  int t = threadIdx.x;
  ushort4 u = *(const ushort4*)(sact + (size_t)n * HID + t * 4);
  float v0 = bf2f(u.x), v1 = bf2f(u.y), v2 = bf2f(u.z), v3 = bf2f(u.w);
  float sum = v0 + v1 + v2 + v3;
  float sq = v0 * v0 + v1 * v1 + v2 * v2 + v3 * v3;
#pragma unroll
  for (int off = 32; off >= 1; off >>= 1) {
    sum += __shfl_down(sum, off);
    sq  += __shfl_down(sq, off);
  }
  __shared__ float rs[3], rq2[3];
  int wv = t >> 6;
  if ((t & 63) == 0) { rs[wv] = sum; rq2[wv] = sq; }
  __syncthreads();
  if (t == 0) {
    float s = rs[0] + rs[1] + rs[2];
    float q = rq2[0] + rq2[1] + rq2[2];
    rs[0] = s / (float)HID;
    rq2[0] = q / (float)HID;
  }
  __syncthreads();
  float mu = rs[0];
  float var = rq2[0] - mu * mu;
  float inv = rsqrtf(var + 1e-5f);
  float4 g = *(const float4*)(gamma + t * 4);
  float4 be = *(const float4*)(beta + t * 4);
  float y0 = (v0 - mu) * inv * g.x + be.x;
  float y1 = (v1 - mu) * inv * g.y + be.y;
  float y2 = (v2 - mu) * inv * g.z + be.z;
  float y3 = (v3 - mu) * inv * g.w + be.w;
  if (fout) {
    float4 o; o.x = y0; o.y = y1; o.z = y2; o.w = y3;
    *(float4*)(fout + (size_t)n * HID + t * 4) = o;
  } else {
    ushort4 o;
    o.x = f2bf(y0); o.y = f2bf(y1); o.z = f2bf(y2); o.w = f2bf(y3);
    *(ushort4*)(hout + (size_t)n * HID + t * 4) = o;
  }
}

extern "C" void kernel_launch(void* const* d_in, const int* in_sizes, int n_in,
                              void* d_out, int out_size, void* d_ws, size_t ws_size,
                              hipStream_t stream) {
  const float* x     = (const float*)d_in[0];
  const float* Wp    = (const float*)d_in[1];
  const float* bp    = (const float*)d_in[2];
  const float* Wl    = (const float*)d_in[3];
  const float* bl    = (const float*)d_in[4];
  const float* Wr    = (const float*)d_in[5];
  const float* gamma = (const float*)d_in[6];
  const float* beta  = (const float*)d_in[7];
  const int*   ei    = (const int*)d_in[8];
  float* out = (float*)d_out;

  const int* src = ei;
  const int* dst = ei + NE;

  // workspace carve (all offsets 16B-aligned).
  // NOTE: k_gemm stages A rows up to m0+255 (<= 50207) unconditionally; rows
  // >= NN read into the NEXT buffer in this carve — allocated, harmless
  // (results masked on store). Keep h, agg, sact adjacent and in this order.
  char* p = (char*)d_ws;
  unsigned short* h    = (unsigned short*)p;              p += (size_t)NN * HID * 2;  // 76.8 MB
  unsigned short* agg  = (unsigned short*)p;              p += (size_t)NN * HID * 2;  // 76.8 MB
  unsigned short* sact = (unsigned short*)p;              p += (size_t)NN * HID * 2;  // 76.8 MB
  unsigned short* Wlb  = (unsigned short*)p;              p += (size_t)NL * HID * HID * 2;
  unsigned short* Wrb  = (unsigned short*)p;              p += (size_t)NL * HID * HID * 2;
  int* deg             = (int*)p;                         p += (size_t)NN * 4;
  int* rowptr          = (int*)p;                         p += (size_t)(NN + 1) * 4 + 12;
  int* cursor          = (int*)p;                         p += (size_t)NN * 4;
  int* csr             = (int*)p;                         p += (size_t)NE * 4;

  // graph build + weight prep
  k_zero2<<<(NN + 255) / 256, 256, 0, stream>>>(deg, cursor, NN);
  int wn4 = NL * HID * HID / 4;
  k_cvt<<<(wn4 + 255) / 256, 256, 0, stream>>>(Wl, Wlb, wn4);
  k_cvt<<<(wn4 + 255) / 256, 256, 0, stream>>>(Wr, Wrb, wn4);
  k_inproj<<<NN, 256, 0, stream>>>(x, Wp, bp, h);
  k_deg<<<(NE + 255) / 256, 256, 0, stream>>>(dst, deg);
  k_scan<<<1, 1024, 0, stream>>>(deg, rowptr);
  k_fill<<<(NE + 255) / 256, 256, 0, stream>>>(src, dst, rowptr, cursor, csr);

  const int ggrid = 8 * 3 * 28;  // 672 = NBANDS*3, XCD-bijective, no dead blocks
  for (int l = 0; l < NL; ++l) {
    k_agg<<<NN, 192, 0, stream>>>(h, csr, rowptr, agg);
    k_gemm<<<ggrid, 512, 0, stream>>>(agg, h,
                                      Wlb + (size_t)l * HID * HID,
                                      Wrb + (size_t)l * HID * HID,
                                      bl + (size_t)l * HID, sact, NN);
    k_ln<<<NN, 192, 0, stream>>>(sact, gamma + (size_t)l * HID, beta + (size_t)l * HID,
                                 h, (l == NL - 1) ? out : nullptr);
  }
}